// Round 9
// baseline (53.714 us; speedup 1.0000x reference)
//
#include <hip/hip_runtime.h>
#include <hip/hip_bf16.h>
#include <hip/hip_fp16.h>
#include <stdint.h>

#define NB 8
#define LQ 256
#define LK 512
#define NH 64
// 2*log2(e): folded into projections so tanh(x) = 1 - 2/(1+exp2(SCALE*x_sum))
#define SCALE 2.8853900817779268f
#define L2E 1.4426950408889634f

// ws layout (f32 slots)
#define QP_OFF   0            // [2048][64]
#define KP_OFF   131072       // [4096][64] k-proj (plain row-major)
#define VBF_OFF  393216       // [8][512][256] bf16 (524288 f32 slots)
#define PML_OFF  917504       // [2048][ns][2]
// pacc (f16) follows pml; sizes depend on nsplit (computed in host code)

extern "C" __device__ float __ocml_exp2_f32(float);
static __device__ __forceinline__ float fexp2(float x) {
#if __has_builtin(__builtin_amdgcn_exp2f)
  return __builtin_amdgcn_exp2f(x);
#else
  return __ocml_exp2_f32(x);
#endif
}
static __device__ __forceinline__ float frcp(float x) {
  return __builtin_amdgcn_rcpf(x);
}
static __device__ __forceinline__ uint16_t f2bf(float f) {
  uint32_t u = __float_as_uint(f);
  uint32_t r = (u + 0x7FFFu + ((u >> 16) & 1u)) >> 16;  // RNE
  return (uint16_t)r;
}

// async global->LDS, 16B per lane: dest = wave-uniform LDS base + lane*16,
// src = per-lane global address. Counts against vmcnt.
typedef const __attribute__((address_space(1))) void* gas_ptr;
typedef __attribute__((address_space(3))) void* las_ptr;
static __device__ __forceinline__ void gload16(const void* g, void* l) {
  __builtin_amdgcn_global_load_lds((gas_ptr)g, (las_ptr)l, 16, 0, 0);
}

// blocks 0..255:   q-projection -> qp[row][h] (scaled)    (128 row-tiles of 16 x 2 hh)
// blocks 256..767: k-projection -> kp[row][h] (scaled)    (256 row-tiles of 16 x 2 hh)
// blocks 768..831: values f32 -> bf16
__global__ __launch_bounds__(256) void proj_kernel(
    const float* __restrict__ queries, const float* __restrict__ keys,
    const float* __restrict__ values,
    const float* __restrict__ Wq, const float* __restrict__ Wk,
    float* __restrict__ qp, float* __restrict__ kp, uint16_t* __restrict__ vbf)
{
  __shared__ float Wt[256][34];   // pad 34: writes 2-way (free), rows 8B-aligned
  const int blk = blockIdx.x;
  const int t = threadIdx.x;

  if (blk >= 768) {
    int base = (blk - 768) * 16384 + t * 4;
#pragma unroll
    for (int it = 0; it < 16; ++it) {
      int idx = base + it * 1024;
      float4 v = *(const float4*)(values + idx);
      uint32_t lo = (uint32_t)f2bf(v.x) | ((uint32_t)f2bf(v.y) << 16);
      uint32_t hi = (uint32_t)f2bf(v.z) | ((uint32_t)f2bf(v.w) << 16);
      uint2 pk = {lo, hi};
      *(uint2*)(vbf + idx) = pk;
    }
    return;
  }

  const bool isQ = (blk < 256);
  const int sub = isQ ? blk : (blk - 256);
  const int tile = sub >> 1;
  const int hh = (sub & 1) * 32;
  const int rowbase = tile * 16;
  const float* __restrict__ X = isQ ? queries : keys;
  const float* __restrict__ W = isQ ? Wq : Wk;
  float* __restrict__ P = isQ ? qp : kp;

#pragma unroll 4
  for (int it = 0; it < 32; ++it) {
    Wt[t][it] = W[(hh + it) * 256 + t];
  }
  __syncthreads();

  const int ty = t >> 4;          // 0..15 -> 1 row each
  const int tx = t & 15;          // 0..15 -> 2 h each
  float a0 = 0.f, a1 = 0.f;

  const float* xr0 = X + (rowbase + ty) * 256;

#pragma unroll 4
  for (int d4 = 0; d4 < 64; ++d4) {
    int d = d4 * 4;
    float4 x0 = *(const float4*)(xr0 + d);
    float2 w0 = *(float2*)&Wt[d + 0][tx * 2];
    float2 w1 = *(float2*)&Wt[d + 1][tx * 2];
    float2 w2 = *(float2*)&Wt[d + 2][tx * 2];
    float2 w3 = *(float2*)&Wt[d + 3][tx * 2];
    a0 = fmaf(x0.x, w0.x, a0); a1 = fmaf(x0.x, w0.y, a1);
    a0 = fmaf(x0.y, w1.x, a0); a1 = fmaf(x0.y, w1.y, a1);
    a0 = fmaf(x0.z, w2.x, a0); a1 = fmaf(x0.z, w2.y, a1);
    a0 = fmaf(x0.w, w3.x, a0); a1 = fmaf(x0.w, w3.y, a1);
  }

  {
    int row = rowbase + ty;
    int h = hh + tx * 2;
    P[row * 64 + h + 0] = a0 * SCALE;
    P[row * 64 + h + 1] = a1 * SCALE;
  }
}

// grid = nsplit*128 WGs of 512 threads (8 waves). wg -> b=wg&7, qg=(wg>>3)&15,
// kh=wg>>7. WG covers 16 q-rows (2 per wave); all 8 waves share one K/V tile.
// Per 32-k tile: double-buffered global_load_lds (3 instr/thread) with counted
// vmcnt(3); raw s_barrier. Scores: lane=(r2,kj), q in 64 VGPRs, w_v s_loads.
// PV: lane=(r2,c) does kk-half for BOTH rows. k-split partials merged after.
// 50KB LDS -> 3 WGs/CU cap; grid 512 = 2 WGs/CU, ALL resident (16 waves/CU,
// 4/SIMD — R6-R8 had ~12 max with tail; occupancy was the diagnosed wall).
// NOTE (R4/R5): no __launch_bounds__ min-waves — forcing occupancy spilled.
__global__ __launch_bounds__(512) void attn_kernel(
    const float* __restrict__ qp, const float* __restrict__ kp,
    const uint16_t* __restrict__ vbf, const float* __restrict__ w_v,
    const int* __restrict__ valid_lens, float* __restrict__ out,
    float* __restrict__ pml, __half* __restrict__ pacc, int nsplit)
{
  __shared__ float kTs[2][32][64];      // [buf][kj][h], 16B chunks XOR-swizzled by kj&7
  __shared__ uint16_t Vs[2][32][256];   // [buf][kj][d] bf16, linear
  __shared__ float p_s[8][2][32];

  const int t = threadIdx.x;
  const int lane = t & 63;
  const int w = t >> 6;         // 0..7
  const int r2 = lane >> 5;     // score: row-half. PV: kk-half. write: row-half.
  const int kj = lane & 31;     // score: k index.  PV: d-chunk c.
  const int wg = blockIdx.x;
  const int b = wg & 7;
  const int qg = (wg >> 3) & 15;
  const int kh = wg >> 7;
  const int row = b * LQ + qg * 16 + w * 2 + r2;

  const int vl = valid_lens[b];
  const int n = (vl > 0) ? vl : LK;   // vl==0 -> uniform softmax over all 512
  const int span = LK / nsplit;
  const int kstart = kh * span;
  int cnt = n - kstart;
  if (cnt > span) cnt = span;
  const int ntiles = (cnt > 0) ? ((cnt + 31) >> 5) : 0;

  if (ntiles == 0) {          // WG-uniform branch (depends on b,kh only)
    if (kj == 0) {
      pml[(row * nsplit + kh) * 2 + 0] = -1e30f;
      pml[(row * nsplit + kh) * 2 + 1] = 0.f;
    }
    return;
  }

  // W1 = sum(w_v) via uniform (scalar) loads
  float W1 = 0.f;
#pragma unroll
  for (int g = 0; g < 16; ++g) {
    float4 wf = *(const float4*)(w_v + g * 4);
    W1 += (wf.x + wf.y) + (wf.z + wf.w);
  }

  // q-row (pre-scaled) in registers — 64 VGPRs, static indexing only
  float qv[64];
  {
    const float* qrow = qp + (size_t)row * 64;
#pragma unroll
    for (int i = 0; i < 16; ++i) {
      float4 v = *(const float4*)(qrow + i * 4);
      qv[i * 4 + 0] = v.x; qv[i * 4 + 1] = v.y;
      qv[i * 4 + 2] = v.z; qv[i * 4 + 3] = v.w;
    }
  }

  const float* kpb = kp + (size_t)(b * LK) * 64;
  const char* vbc = (const char*)(vbf + (size_t)b * LK * 256);

  // DMA one 32-k tile into buffer BUF: exactly 3 gload16 per thread.
  // k (8KB): thread t -> row t>>4 (wave w covers rows w*4..w*4+3), phys chunk
  // t&15, src chunk = phys^(row&7) (XOR involution; LDS dest linear).
  // V (16KB): wave w instr j covers rows w*4+j*2..+2 (1KB linear each).
#define STAGE(BUF, K0) do { \
    int kjr = (t >> 4); \
    int cph = t & 15; \
    gload16(kpb + (size_t)((K0) + kjr) * 64 + (cph ^ (kjr & 7)) * 4, \
            &kTs[BUF][w * 4][0]); \
    gload16(vbc + (size_t)((K0) + w * 4 + 0) * 512 + (lane >> 5) * 512 + (lane & 31) * 16, \
            &Vs[BUF][w * 4 + 0][0]); \
    gload16(vbc + (size_t)((K0) + w * 4 + 2) * 512 + (lane >> 5) * 512 + (lane & 31) * 16, \
            &Vs[BUF][w * 4 + 2][0]); \
  } while (0)

  float m = -1e30f, l = 0.f;
  float acc[16];                // [0..7] row0 partial, [8..15] row1 (this kk-half)
#pragma unroll
  for (int i = 0; i < 16; ++i) acc[i] = 0.f;

  STAGE(0, kstart);

  for (int tt = 0; tt < ntiles; ++tt) {
    const int cur = tt & 1;
    const int k0 = kstart + tt * 32;
    // T4 counted wait: issue next-tile DMA, wait only for THIS tile's 3
    // (newest 3 = next tile stay in flight across the barrier). Last tile: 0.
    if (tt + 1 < ntiles) {
      STAGE(cur ^ 1, k0 + 32);
      asm volatile("s_waitcnt vmcnt(3)" ::: "memory");
    } else {
      asm volatile("s_waitcnt vmcnt(0)" ::: "memory");
    }
    __builtin_amdgcn_sched_barrier(0);
    __builtin_amdgcn_s_barrier();        // all waves' tile-tt portions landed
    __builtin_amdgcn_sched_barrier(0);
    __builtin_amdgcn_s_setprio(1);

    // ---- scores: lane = (r2, kj) computes row(r2)'s score at k0+kj ----
    float r0 = 0.f, r1 = 0.f, r2a = 0.f, r3 = 0.f;
#pragma unroll
    for (int g = 0; g < 16; ++g) {
      float4 kf = *(const float4*)&kTs[cur][kj][((g ^ (kj & 7)) << 2)];
      float4 wf = *(const float4*)(w_v + g * 4);        // uniform -> s_load
      r0  = fmaf(wf.x, frcp(1.f + fexp2(qv[g * 4 + 0] + kf.x)), r0);
      r1  = fmaf(wf.y, frcp(1.f + fexp2(qv[g * 4 + 1] + kf.y)), r1);
      r2a = fmaf(wf.z, frcp(1.f + fexp2(qv[g * 4 + 2] + kf.z)), r2a);
      r3  = fmaf(wf.w, frcp(1.f + fexp2(qv[g * 4 + 3] + kf.w)), r3);
    }
    float racc = (r0 + r1) + (r2a + r3);

    float score;
    int kg = k0 + kj;
    if (vl == 0)      score = 0.f;
    else if (kg < n)  score = fmaf(-2.f, racc, W1);
    else              score = -1e30f;

    // ---- online softmax (32-wide, per row-half) ----
    float mt = score;
#pragma unroll
    for (int s = 16; s; s >>= 1) mt = fmaxf(mt, __shfl_xor(mt, s, 64));
    float mnew = fmaxf(m, mt);
    float alpha = fexp2((m - mnew) * L2E);
    float p = fexp2((score - mnew) * L2E);
    m = mnew;
    float S = p;
#pragma unroll
    for (int s = 16; s; s >>= 1) S += __shfl_xor(S, s, 64);
    l = l * alpha + S;
    p_s[w][r2][kj] = p;   // same-wave handoff (lgkmcnt by compiler)

    // ---- PV: lane = (r2, c): kk in [r2*16,+16), d = c*8..+8, BOTH rows ----
    float alpha_x = __shfl_xor(alpha, 32, 64);          // other row-half's alpha
    float a0 = (r2 == 0) ? alpha : alpha_x;             // row0 alpha
    float a1 = (r2 == 0) ? alpha_x : alpha;             // row1 alpha
#pragma unroll
    for (int i = 0; i < 8; ++i)  acc[i] *= a0;
#pragma unroll
    for (int i = 8; i < 16; ++i) acc[i] *= a1;

    const int c = kj;           // d-chunk
#pragma unroll
    for (int i4 = 0; i4 < 4; ++i4) {
      float4 p0 = *(const float4*)&p_s[w][0][r2 * 16 + i4 * 4];   // row0 p
      float4 p1 = *(const float4*)&p_s[w][1][r2 * 16 + i4 * 4];   // row1 p
#pragma unroll
      for (int jj = 0; jj < 4; ++jj) {
        int kk = r2 * 16 + i4 * 4 + jj;
        uint4 vv = *(const uint4*)&Vs[cur][kk][c * 8];
        float pj0 = (jj == 0) ? p0.x : (jj == 1) ? p0.y : (jj == 2) ? p0.z : p0.w;
        float pj1 = (jj == 0) ? p1.x : (jj == 1) ? p1.y : (jj == 2) ? p1.z : p1.w;
        float f0 = __uint_as_float(vv.x << 16);
        float f1 = __uint_as_float(vv.x & 0xFFFF0000u);
        float f2 = __uint_as_float(vv.y << 16);
        float f3 = __uint_as_float(vv.y & 0xFFFF0000u);
        float f4 = __uint_as_float(vv.z << 16);
        float f5 = __uint_as_float(vv.z & 0xFFFF0000u);
        float f6 = __uint_as_float(vv.w << 16);
        float f7 = __uint_as_float(vv.w & 0xFFFF0000u);
        acc[0] = fmaf(pj0, f0, acc[0]);   acc[8]  = fmaf(pj1, f0, acc[8]);
        acc[1] = fmaf(pj0, f1, acc[1]);   acc[9]  = fmaf(pj1, f1, acc[9]);
        acc[2] = fmaf(pj0, f2, acc[2]);   acc[10] = fmaf(pj1, f2, acc[10]);
        acc[3] = fmaf(pj0, f3, acc[3]);   acc[11] = fmaf(pj1, f3, acc[11]);
        acc[4] = fmaf(pj0, f4, acc[4]);   acc[12] = fmaf(pj1, f4, acc[12]);
        acc[5] = fmaf(pj0, f5, acc[5]);   acc[13] = fmaf(pj1, f5, acc[13]);
        acc[6] = fmaf(pj0, f6, acc[6]);   acc[14] = fmaf(pj1, f6, acc[14]);
        acc[7] = fmaf(pj0, f7, acc[7]);   acc[15] = fmaf(pj1, f7, acc[15]);
      }
    }
    __builtin_amdgcn_s_setprio(0);
    __builtin_amdgcn_sched_barrier(0);
    __builtin_amdgcn_s_barrier();   // readers of buf[cur] done before overwrite
  }
#undef STAGE

  // combine the two kk-half partials
#pragma unroll
  for (int i = 0; i < 16; ++i) acc[i] += __shfl_xor(acc[i], 32, 64);

  // lane (r2,c) writes its own row (r2) — m,l are correct for that row here.
  const float* accr = acc + r2 * 8;
  if (nsplit == 1) {
    float inv = 1.f / l;
    float4 o0 = {accr[0] * inv, accr[1] * inv, accr[2] * inv, accr[3] * inv};
    float4 o1 = {accr[4] * inv, accr[5] * inv, accr[6] * inv, accr[7] * inv};
    float* op = out + (size_t)row * 256 + kj * 8;
    *(float4*)(op + 0) = o0;
    *(float4*)(op + 4) = o1;
  } else {
    if (kj == 0) {
      pml[(row * nsplit + kh) * 2 + 0] = m;
      pml[(row * nsplit + kh) * 2 + 1] = l;
    }
    __half2 h0 = __floats2half2_rn(accr[0], accr[1]);
    __half2 h1 = __floats2half2_rn(accr[2], accr[3]);
    __half2 h2 = __floats2half2_rn(accr[4], accr[5]);
    __half2 h3 = __floats2half2_rn(accr[6], accr[7]);
    uint4 pk = {*(uint32_t*)&h0, *(uint32_t*)&h1, *(uint32_t*)&h2, *(uint32_t*)&h3};
    *(uint4*)(pacc + ((size_t)(row * nsplit + kh)) * 256 + kj * 8) = pk;
  }
}

// merge k-split partials: 256 blocks x 256 thr; 8 rows/block, 32 lanes/row.
__global__ __launch_bounds__(256) void merge_kernel(
    const float* __restrict__ pml, const __half* __restrict__ pacc,
    float* __restrict__ out, int nsplit)
{
  const int t = threadIdx.x;
  const int row = blockIdx.x * 8 + (t >> 5);
  const int d8 = t & 31;

  float ms = -1e30f;
  for (int kh = 0; kh < nsplit; ++kh)
    ms = fmaxf(ms, pml[(row * nsplit + kh) * 2]);

  float L = 0.f;
  float o[8];
#pragma unroll
  for (int i = 0; i < 8; ++i) o[i] = 0.f;

  for (int kh = 0; kh < nsplit; ++kh) {
    float mk = pml[(row * nsplit + kh) * 2 + 0];
    float lk = pml[(row * nsplit + kh) * 2 + 1];
    if (lk > 0.f) {
      float e = fexp2((mk - ms) * L2E);
      L += e * lk;
      uint4 pk = *(const uint4*)(pacc + ((size_t)(row * nsplit + kh)) * 256 + d8 * 8);
      __half2 h0 = *(__half2*)&pk.x, h1 = *(__half2*)&pk.y;
      __half2 h2 = *(__half2*)&pk.z, h3 = *(__half2*)&pk.w;
      float2 f0 = __half22float2(h0), f1 = __half22float2(h1);
      float2 f2 = __half22float2(h2), f3 = __half22float2(h3);
      o[0] = fmaf(e, f0.x, o[0]); o[1] = fmaf(e, f0.y, o[1]);
      o[2] = fmaf(e, f1.x, o[2]); o[3] = fmaf(e, f1.y, o[3]);
      o[4] = fmaf(e, f2.x, o[4]); o[5] = fmaf(e, f2.y, o[5]);
      o[6] = fmaf(e, f3.x, o[6]); o[7] = fmaf(e, f3.y, o[7]);
    }
  }
  float inv = 1.f / L;
  float4 o0 = {o[0] * inv, o[1] * inv, o[2] * inv, o[3] * inv};
  float4 o1 = {o[4] * inv, o[5] * inv, o[6] * inv, o[7] * inv};
  float* op = out + (size_t)row * 256 + d8 * 8;
  *(float4*)(op + 0) = o0;
  *(float4*)(op + 4) = o1;
}

extern "C" void kernel_launch(void* const* d_in, const int* in_sizes, int n_in,
                              void* d_out, int out_size, void* d_ws, size_t ws_size,
                              hipStream_t stream) {
  const float* queries    = (const float*)d_in[0];
  const float* keys       = (const float*)d_in[1];
  const float* values     = (const float*)d_in[2];
  const int*   valid_lens = (const int*)d_in[3];
  const float* Wq         = (const float*)d_in[4];
  const float* Wk         = (const float*)d_in[5];
  const float* w_v        = (const float*)d_in[6];
  float* out = (float*)d_out;

  float* ws = (float*)d_ws;
  float* qp  = ws + QP_OFF;
  float* kp  = ws + KP_OFF;
  uint16_t* vbf = (uint16_t*)(ws + VBF_OFF);
  float* pml = ws + PML_OFF;

  // bytes needed: base 3,670,016 + pml 2048*ns*8 + pacc 2048*ns*512
  int nsplit;
  if      (ws_size >= (size_t)PML_OFF * 4 + 2048u * 4 * 8 + 2048u * 4 * 512) nsplit = 4;
  else if (ws_size >= (size_t)PML_OFF * 4 + 2048u * 2 * 8 + 2048u * 2 * 512) nsplit = 2;
  else nsplit = 1;
  __half* pacc = (__half*)(pml + (size_t)2048 * nsplit * 2);

  hipLaunchKernelGGL(proj_kernel, dim3(832), dim3(256), 0, stream,
                     queries, keys, values, Wq, Wk, qp, kp, vbf);
  hipLaunchKernelGGL(attn_kernel, dim3(nsplit * 128), dim3(512), 0, stream,
                     qp, kp, vbf, w_v, valid_lens, out, pml, pacc, nsplit);
  if (nsplit > 1) {
    hipLaunchKernelGGL(merge_kernel, dim3(256), dim3(256), 0, stream,
                       pml, pacc, out, nsplit);
  }
}

// Round 10
// 48.418 us; speedup vs baseline: 1.1094x; 1.1094x over previous
//
#include <hip/hip_runtime.h>
#include <hip/hip_bf16.h>
#include <hip/hip_fp16.h>
#include <stdint.h>

#define NB 8
#define LQ 256
#define LK 512
#define NH 64
// 2*log2(e): folded into projections so tanh(x) = 1 - 2/(1+exp2(SCALE*x_sum))
#define SCALE 2.8853900817779268f
#define L2E 1.4426950408889634f

// ws layout (f32 slots)
#define QP_OFF   0            // [2048][64]
#define KP_OFF   131072       // [4096][64] k-proj (plain row-major)
#define VBF_OFF  393216       // [8][512][256] bf16 (524288 f32 slots)
#define PML_OFF  917504       // [2048][ns][2]
// pacc (f16) follows pml; sizes depend on nsplit (computed in host code)

extern "C" __device__ float __ocml_exp2_f32(float);
static __device__ __forceinline__ float fexp2(float x) {
#if __has_builtin(__builtin_amdgcn_exp2f)
  return __builtin_amdgcn_exp2f(x);
#else
  return __ocml_exp2_f32(x);
#endif
}
static __device__ __forceinline__ float frcp(float x) {
  return __builtin_amdgcn_rcpf(x);
}
static __device__ __forceinline__ uint16_t f2bf(float f) {
  uint32_t u = __float_as_uint(f);
  uint32_t r = (u + 0x7FFFu + ((u >> 16) & 1u)) >> 16;  // RNE
  return (uint16_t)r;
}

// async global->LDS, 16B per lane: dest = wave-uniform LDS base + lane*16,
// src = per-lane global address. Counts against vmcnt.
typedef const __attribute__((address_space(1))) void* gas_ptr;
typedef __attribute__((address_space(3))) void* las_ptr;
static __device__ __forceinline__ void gload16(const void* g, void* l) {
  __builtin_amdgcn_global_load_lds((gas_ptr)g, (las_ptr)l, 16, 0, 0);
}

// blocks 0..255:   q-projection -> qp[row][h] (scaled)    (128 row-tiles of 16 x 2 hh)
// blocks 256..767: k-projection -> kp[row][h] (scaled)    (256 row-tiles of 16 x 2 hh)
// blocks 768..831: values f32 -> bf16
// X tile staged in LDS: R9 analysis — 16 tx-threads per row re-read X 16x from
// global (~96MB L2 traffic); staging kills the redundancy.
__global__ __launch_bounds__(256) void proj_kernel(
    const float* __restrict__ queries, const float* __restrict__ keys,
    const float* __restrict__ values,
    const float* __restrict__ Wq, const float* __restrict__ Wk,
    float* __restrict__ qp, float* __restrict__ kp, uint16_t* __restrict__ vbf)
{
  __shared__ float Wt[256][34];   // [d][h_local], pad 34 (writes 2-way = free)
  __shared__ float Xs[16][260];   // row tile, pad 260 (bank shift 4/row)
  const int blk = blockIdx.x;
  const int t = threadIdx.x;

  if (blk >= 768) {
    int base = (blk - 768) * 16384 + t * 4;
#pragma unroll
    for (int it = 0; it < 16; ++it) {
      int idx = base + it * 1024;
      float4 v = *(const float4*)(values + idx);
      uint32_t lo = (uint32_t)f2bf(v.x) | ((uint32_t)f2bf(v.y) << 16);
      uint32_t hi = (uint32_t)f2bf(v.z) | ((uint32_t)f2bf(v.w) << 16);
      uint2 pk = {lo, hi};
      *(uint2*)(vbf + idx) = pk;
    }
    return;
  }

  const bool isQ = (blk < 256);
  const int sub = isQ ? blk : (blk - 256);
  const int tile = sub >> 1;
  const int hh = (sub & 1) * 32;
  const int rowbase = tile * 16;
  const float* __restrict__ X = isQ ? queries : keys;
  const float* __restrict__ W = isQ ? Wq : Wk;
  float* __restrict__ P = isQ ? qp : kp;

  // stage W[hh..hh+31][0..255] transposed
#pragma unroll 4
  for (int it = 0; it < 32; ++it) {
    Wt[t][it] = W[(hh + it) * 256 + t];
  }
  // stage X rows [rowbase..rowbase+16) — each element read ONCE
#pragma unroll
  for (int i = 0; i < 4; ++i) {
    int flat4 = t + i * 256;          // float4 index over 16x64
    int r = flat4 >> 6, d4 = flat4 & 63;
    float4 v = *(const float4*)(X + (size_t)(rowbase + r) * 256 + d4 * 4);
    *(float4*)&Xs[r][d4 * 4] = v;
  }
  __syncthreads();

  const int ty = t >> 4;          // 0..15 -> 1 row each
  const int tx = t & 15;          // 0..15 -> 2 h each
  float a0 = 0.f, a1 = 0.f;

#pragma unroll 4
  for (int d4 = 0; d4 < 64; ++d4) {
    int d = d4 * 4;
    float4 x0 = *(const float4*)&Xs[ty][d];
    float2 w0 = *(float2*)&Wt[d + 0][tx * 2];
    float2 w1 = *(float2*)&Wt[d + 1][tx * 2];
    float2 w2 = *(float2*)&Wt[d + 2][tx * 2];
    float2 w3 = *(float2*)&Wt[d + 3][tx * 2];
    a0 = fmaf(x0.x, w0.x, a0); a1 = fmaf(x0.x, w0.y, a1);
    a0 = fmaf(x0.y, w1.x, a0); a1 = fmaf(x0.y, w1.y, a1);
    a0 = fmaf(x0.z, w2.x, a0); a1 = fmaf(x0.z, w2.y, a1);
    a0 = fmaf(x0.w, w3.x, a0); a1 = fmaf(x0.w, w3.y, a1);
  }

  {
    int row = rowbase + ty;
    int h = hh + tx * 2;
    P[row * 64 + h + 0] = a0 * SCALE;
    P[row * 64 + h + 1] = a1 * SCALE;
  }
}

// grid = nsplit*256 WGs of 256 threads (4 waves). wg -> b=wg&7, qg=(wg>>3)&31,
// kh=wg>>8. WG = 8 q-rows (2/wave). Per 32-k tile: k staged via dbuf
// global_load_lds (2 instr/thread, counted vmcnt); V read DIRECT from global
// (L2-hot, each b128 instr coalesces to one 512B row); q in LDS (broadcast).
// acc[8] only (each lane: own row, all 32 kk) -> target VGPR<=64 for
// 8 waves/SIMD; LDS 19KB -> 8 WGs/CU; nsplit=8 -> 2048 WGs = 8/CU resident.
// R9 lesson: occupancy is the wall (VALU-busy ~9us vs 30-40us elapsed).
__global__ __launch_bounds__(256) void attn_kernel(
    const float* __restrict__ qp, const float* __restrict__ kp,
    const uint16_t* __restrict__ vbf, const float* __restrict__ w_v,
    const int* __restrict__ valid_lens, float* __restrict__ out,
    float* __restrict__ pml, __half* __restrict__ pacc, int nsplit)
{
  __shared__ float kTs[2][32][64];    // [buf][kj][h], 16B chunks XOR-swizzled by kj&7
  __shared__ float q_s[4][2][64];     // [w][r2][h]
  __shared__ float p_s[4][2][32];

  const int t = threadIdx.x;
  const int lane = t & 63;
  const int w = t >> 6;
  const int r2 = lane >> 5;     // row-half (score row, PV row, write row)
  const int kx = lane & 31;     // score: k index. PV/write: d-chunk c.
  const int wg = blockIdx.x;
  const int b = wg & 7;
  const int qg = (wg >> 3) & 31;
  const int kh = wg >> 8;
  const int row = b * LQ + qg * 8 + w * 2 + r2;

  const int vl = valid_lens[b];
  const int n = (vl > 0) ? vl : LK;   // vl==0 -> uniform softmax over all 512
  const int span = LK / nsplit;
  const int kstart = kh * span;
  int cnt = n - kstart;
  if (cnt > span) cnt = span;
  const int ntiles = (cnt > 0) ? ((cnt + 31) >> 5) : 0;

  if (ntiles == 0) {          // WG-uniform branch (depends on b,kh only)
    if (kx == 0) {
      pml[(row * nsplit + kh) * 2 + 0] = -1e30f;
      pml[(row * nsplit + kh) * 2 + 1] = 0.f;
    }
    return;
  }

  // stage this WG's 8 q-rows (own-wave slice: thread t writes q_s flat [2t])
  {
    const float2* qsrc = (const float2*)(qp + (size_t)(b * LQ + qg * 8) * 64);
    ((float2*)q_s)[t] = qsrc[t];
    asm volatile("s_waitcnt lgkmcnt(0)" ::: "memory");
  }

  // W1 = sum(w_v) via uniform (scalar) loads
  float W1 = 0.f;
#pragma unroll
  for (int g = 0; g < 16; ++g) {
    float4 wf = *(const float4*)(w_v + g * 4);
    W1 += (wf.x + wf.y) + (wf.z + wf.w);
  }

  const float* kpb = kp + (size_t)(b * LK) * 64;
  const char* vbc = (const char*)(vbf + (size_t)b * LK * 256);

  // DMA one 32-k k-tile into buffer BUF: exactly 2 gload16 per thread.
  // Load j (j=0,1): lane l -> row w*4 + j*16 + (l>>4), phys chunk l&15,
  // src chunk = phys ^ (row&7) (XOR involution; LDS dest linear).
#define STAGE(BUF, K0) do { \
    int r0_ = w * 4 + (lane >> 4); \
    int cph = lane & 15; \
    gload16(kpb + (size_t)((K0) + r0_) * 64 + (cph ^ (r0_ & 7)) * 4, \
            &kTs[BUF][w * 4][0]); \
    int r1_ = r0_ + 16; \
    gload16(kpb + (size_t)((K0) + r1_) * 64 + (cph ^ (r1_ & 7)) * 4, \
            &kTs[BUF][w * 4 + 16][0]); \
  } while (0)

  float m = -1e30f, l = 0.f;
  float acc[8];
#pragma unroll
  for (int i = 0; i < 8; ++i) acc[i] = 0.f;

  STAGE(0, kstart);

  for (int tt = 0; tt < ntiles; ++tt) {
    const int cur = tt & 1;
    const int k0 = kstart + tt * 32;
    if (tt + 1 < ntiles) {
      STAGE(cur ^ 1, k0 + 32);
      asm volatile("s_waitcnt vmcnt(2)" ::: "memory");
    } else {
      asm volatile("s_waitcnt vmcnt(0)" ::: "memory");
    }
    __builtin_amdgcn_sched_barrier(0);
    __builtin_amdgcn_s_barrier();        // all waves' tile-tt k landed
    __builtin_amdgcn_sched_barrier(0);
    __builtin_amdgcn_s_setprio(1);

    // ---- scores: lane = (r2, kx) computes row(r2)'s score at k0+kx ----
    float r0 = 0.f, r1 = 0.f, r2a = 0.f, r3 = 0.f;
#pragma unroll
    for (int g = 0; g < 16; ++g) {
      float4 kf = *(const float4*)&kTs[cur][kx][((g ^ (kx & 7)) << 2)];
      float4 qf = *(const float4*)&q_s[w][r2][g * 4];   // 2 addrs/wave -> broadcast
      float4 wf = *(const float4*)(w_v + g * 4);        // uniform -> s_load
      r0  = fmaf(wf.x, frcp(1.f + fexp2(qf.x + kf.x)), r0);
      r1  = fmaf(wf.y, frcp(1.f + fexp2(qf.y + kf.y)), r1);
      r2a = fmaf(wf.z, frcp(1.f + fexp2(qf.z + kf.z)), r2a);
      r3  = fmaf(wf.w, frcp(1.f + fexp2(qf.w + kf.w)), r3);
    }
    float racc = (r0 + r1) + (r2a + r3);

    float score;
    int kg = k0 + kx;
    if (vl == 0)      score = 0.f;
    else if (kg < n)  score = fmaf(-2.f, racc, W1);
    else              score = -1e30f;

    // ---- online softmax (32-wide, per row-half) ----
    float mt = score;
#pragma unroll
    for (int s = 16; s; s >>= 1) mt = fmaxf(mt, __shfl_xor(mt, s, 64));
    float mnew = fmaxf(m, mt);
    float alpha = fexp2((m - mnew) * L2E);
    float p = fexp2((score - mnew) * L2E);
    m = mnew;
    float S = p;
#pragma unroll
    for (int s = 16; s; s >>= 1) S += __shfl_xor(S, s, 64);
    l = l * alpha + S;
    p_s[w][r2][kx] = p;   // same-wave handoff (lgkmcnt by compiler)

    // ---- PV: lane = (r2, c): own row, all 32 kk, d = c*8..+8; V from L2 ----
#pragma unroll
    for (int i = 0; i < 8; ++i) acc[i] *= alpha;
    const int c = kx;
#pragma unroll
    for (int i4 = 0; i4 < 8; ++i4) {
      float4 pf = *(const float4*)&p_s[w][r2][i4 * 4];  // 2 addrs/wave
#pragma unroll
      for (int jj = 0; jj < 4; ++jj) {
        int kk = i4 * 4 + jj;
        // both halves read the same 512B row -> one coalesced fetch
        uint4 vv = *(const uint4*)(vbc + (size_t)(k0 + kk) * 512 + c * 16);
        float pj = (jj == 0) ? pf.x : (jj == 1) ? pf.y : (jj == 2) ? pf.z : pf.w;
        float f0 = __uint_as_float(vv.x << 16);
        float f1 = __uint_as_float(vv.x & 0xFFFF0000u);
        float f2 = __uint_as_float(vv.y << 16);
        float f3 = __uint_as_float(vv.y & 0xFFFF0000u);
        float f4 = __uint_as_float(vv.z << 16);
        float f5 = __uint_as_float(vv.z & 0xFFFF0000u);
        float f6 = __uint_as_float(vv.w << 16);
        float f7 = __uint_as_float(vv.w & 0xFFFF0000u);
        acc[0] = fmaf(pj, f0, acc[0]);
        acc[1] = fmaf(pj, f1, acc[1]);
        acc[2] = fmaf(pj, f2, acc[2]);
        acc[3] = fmaf(pj, f3, acc[3]);
        acc[4] = fmaf(pj, f4, acc[4]);
        acc[5] = fmaf(pj, f5, acc[5]);
        acc[6] = fmaf(pj, f6, acc[6]);
        acc[7] = fmaf(pj, f7, acc[7]);
      }
    }
    __builtin_amdgcn_s_setprio(0);
    __builtin_amdgcn_sched_barrier(0);
    __builtin_amdgcn_s_barrier();   // readers of kTs[cur] done before overwrite
  }
#undef STAGE

  // lane (r2,c) writes its own row at d-chunk c
  if (nsplit == 1) {
    float inv = 1.f / l;
    float4 o0 = {acc[0] * inv, acc[1] * inv, acc[2] * inv, acc[3] * inv};
    float4 o1 = {acc[4] * inv, acc[5] * inv, acc[6] * inv, acc[7] * inv};
    float* op = out + (size_t)row * 256 + kx * 8;
    *(float4*)(op + 0) = o0;
    *(float4*)(op + 4) = o1;
  } else {
    if (kx == 0) {
      pml[(row * nsplit + kh) * 2 + 0] = m;
      pml[(row * nsplit + kh) * 2 + 1] = l;
    }
    __half2 h0 = __floats2half2_rn(acc[0], acc[1]);
    __half2 h1 = __floats2half2_rn(acc[2], acc[3]);
    __half2 h2 = __floats2half2_rn(acc[4], acc[5]);
    __half2 h3 = __floats2half2_rn(acc[6], acc[7]);
    uint4 pk = {*(uint32_t*)&h0, *(uint32_t*)&h1, *(uint32_t*)&h2, *(uint32_t*)&h3};
    *(uint4*)(pacc + ((size_t)(row * nsplit + kh)) * 256 + kx * 8) = pk;
  }
}

// merge k-split partials: 256 blocks x 256 thr; 8 rows/block, 32 lanes/row.
__global__ __launch_bounds__(256) void merge_kernel(
    const float* __restrict__ pml, const __half* __restrict__ pacc,
    float* __restrict__ out, int nsplit)
{
  const int t = threadIdx.x;
  const int row = blockIdx.x * 8 + (t >> 5);
  const int d8 = t & 31;

  float ms = -1e30f;
  for (int kh = 0; kh < nsplit; ++kh)
    ms = fmaxf(ms, pml[(row * nsplit + kh) * 2]);

  float L = 0.f;
  float o[8];
#pragma unroll
  for (int i = 0; i < 8; ++i) o[i] = 0.f;

  for (int kh = 0; kh < nsplit; ++kh) {
    float mk = pml[(row * nsplit + kh) * 2 + 0];
    float lk = pml[(row * nsplit + kh) * 2 + 1];
    if (lk > 0.f) {
      float e = fexp2((mk - ms) * L2E);
      L += e * lk;
      uint4 pk = *(const uint4*)(pacc + ((size_t)(row * nsplit + kh)) * 256 + d8 * 8);
      __half2 h0 = *(__half2*)&pk.x, h1 = *(__half2*)&pk.y;
      __half2 h2 = *(__half2*)&pk.z, h3 = *(__half2*)&pk.w;
      float2 f0 = __half22float2(h0), f1 = __half22float2(h1);
      float2 f2 = __half22float2(h2), f3 = __half22float2(h3);
      o[0] = fmaf(e, f0.x, o[0]); o[1] = fmaf(e, f0.y, o[1]);
      o[2] = fmaf(e, f1.x, o[2]); o[3] = fmaf(e, f1.y, o[3]);
      o[4] = fmaf(e, f2.x, o[4]); o[5] = fmaf(e, f2.y, o[5]);
      o[6] = fmaf(e, f3.x, o[6]); o[7] = fmaf(e, f3.y, o[7]);
    }
  }
  float inv = 1.f / L;
  float4 o0 = {o[0] * inv, o[1] * inv, o[2] * inv, o[3] * inv};
  float4 o1 = {o[4] * inv, o[5] * inv, o[6] * inv, o[7] * inv};
  float* op = out + (size_t)row * 256 + d8 * 8;
  *(float4*)(op + 0) = o0;
  *(float4*)(op + 4) = o1;
}

extern "C" void kernel_launch(void* const* d_in, const int* in_sizes, int n_in,
                              void* d_out, int out_size, void* d_ws, size_t ws_size,
                              hipStream_t stream) {
  const float* queries    = (const float*)d_in[0];
  const float* keys       = (const float*)d_in[1];
  const float* values     = (const float*)d_in[2];
  const int*   valid_lens = (const int*)d_in[3];
  const float* Wq         = (const float*)d_in[4];
  const float* Wk         = (const float*)d_in[5];
  const float* w_v        = (const float*)d_in[6];
  float* out = (float*)d_out;

  float* ws = (float*)d_ws;
  float* qp  = ws + QP_OFF;
  float* kp  = ws + KP_OFF;
  uint16_t* vbf = (uint16_t*)(ws + VBF_OFF);
  float* pml = ws + PML_OFF;

  // bytes needed: base 3,670,016 + pml 2048*ns*8 + pacc 2048*ns*512
  int nsplit;
  if      (ws_size >= (size_t)PML_OFF * 4 + 2048u * 8 * 8 + 2048u * 8 * 512) nsplit = 8;
  else if (ws_size >= (size_t)PML_OFF * 4 + 2048u * 4 * 8 + 2048u * 4 * 512) nsplit = 4;
  else if (ws_size >= (size_t)PML_OFF * 4 + 2048u * 2 * 8 + 2048u * 2 * 512) nsplit = 2;
  else nsplit = 1;
  __half* pacc = (__half*)(pml + (size_t)2048 * nsplit * 2);

  hipLaunchKernelGGL(proj_kernel, dim3(832), dim3(256), 0, stream,
                     queries, keys, values, Wq, Wk, qp, kp, vbf);
  hipLaunchKernelGGL(attn_kernel, dim3(nsplit * 256), dim3(256), 0, stream,
                     qp, kp, vbf, w_v, valid_lens, out, pml, pacc, nsplit);
  if (nsplit > 1) {
    hipLaunchKernelGGL(merge_kernel, dim3(256), dim3(256), 0, stream,
                       pml, pacc, out, nsplit);
  }
}

// Round 11
// 45.262 us; speedup vs baseline: 1.1867x; 1.0697x over previous
//
#include <hip/hip_runtime.h>
#include <hip/hip_bf16.h>
#include <hip/hip_fp16.h>
#include <stdint.h>

#define NB 8
#define LQ 256
#define LK 512
#define NH 64
// 2*log2(e): folded into projections so tanh(x) = 1 - 2/(1+exp2(SCALE*x_sum))
#define SCALE 2.8853900817779268f
#define L2E 1.4426950408889634f

// ws layout (f32 slots)
#define QP_OFF   0            // [2048][64]
#define KP_OFF   131072       // [4096][64] k-proj (plain row-major)
#define VBF_OFF  393216       // [8][512][256] bf16 (524288 f32 slots)
#define PL_OFF   917504       // [2048][ns] l-sums (f32)
// pacc (f32) follows pl; [2048][ns][256]

extern "C" __device__ float __ocml_exp2_f32(float);
static __device__ __forceinline__ float fexp2(float x) {
#if __has_builtin(__builtin_amdgcn_exp2f)
  return __builtin_amdgcn_exp2f(x);
#else
  return __ocml_exp2_f32(x);
#endif
}
static __device__ __forceinline__ float frcp(float x) {
  return __builtin_amdgcn_rcpf(x);
}
static __device__ __forceinline__ uint16_t f2bf(float f) {
  uint32_t u = __float_as_uint(f);
  uint32_t r = (u + 0x7FFFu + ((u >> 16) & 1u)) >> 16;  // RNE
  return (uint16_t)r;
}

// async global->LDS, 16B per lane: dest = wave-uniform LDS base + lane*16,
// src = per-lane global address. Counts against vmcnt.
typedef const __attribute__((address_space(1))) void* gas_ptr;
typedef __attribute__((address_space(3))) void* las_ptr;
static __device__ __forceinline__ void gload16(const void* g, void* l) {
  __builtin_amdgcn_global_load_lds((gas_ptr)g, (las_ptr)l, 16, 0, 0);
}

// blocks 0..255:   q-projection -> qp[row][h] (scaled)    (128 row-tiles of 16 x 2 hh)
// blocks 256..767: k-projection -> kp[row][h] (scaled)    (256 row-tiles of 16 x 2 hh)
// blocks 768..831: values f32 -> bf16
__global__ __launch_bounds__(256) void proj_kernel(
    const float* __restrict__ queries, const float* __restrict__ keys,
    const float* __restrict__ values,
    const float* __restrict__ Wq, const float* __restrict__ Wk,
    float* __restrict__ qp, float* __restrict__ kp, uint16_t* __restrict__ vbf)
{
  __shared__ float Wt[256][34];   // [d][h_local], pad 34 (writes 2-way = free)
  __shared__ float Xs[16][260];   // row tile, pad 260 (row rotates 1 bank)
  const int blk = blockIdx.x;
  const int t = threadIdx.x;

  if (blk >= 768) {
    int base = (blk - 768) * 16384 + t * 4;
#pragma unroll
    for (int it = 0; it < 16; ++it) {
      int idx = base + it * 1024;
      float4 v = *(const float4*)(values + idx);
      uint32_t lo = (uint32_t)f2bf(v.x) | ((uint32_t)f2bf(v.y) << 16);
      uint32_t hi = (uint32_t)f2bf(v.z) | ((uint32_t)f2bf(v.w) << 16);
      uint2 pk = {lo, hi};
      *(uint2*)(vbf + idx) = pk;
    }
    return;
  }

  const bool isQ = (blk < 256);
  const int sub = isQ ? blk : (blk - 256);
  const int tile = sub >> 1;
  const int hh = (sub & 1) * 32;
  const int rowbase = tile * 16;
  const float* __restrict__ X = isQ ? queries : keys;
  const float* __restrict__ W = isQ ? Wq : Wk;
  float* __restrict__ P = isQ ? qp : kp;

  // stage W[hh..hh+31][0..255] transposed
#pragma unroll 4
  for (int it = 0; it < 32; ++it) {
    Wt[t][it] = W[(hh + it) * 256 + t];
  }
  // stage X rows [rowbase..rowbase+16) — each element read ONCE (16x redundancy fix)
#pragma unroll
  for (int i = 0; i < 4; ++i) {
    int flat4 = t + i * 256;          // float4 index over 16x64
    int r = flat4 >> 6, d4 = flat4 & 63;
    float4 v = *(const float4*)(X + (size_t)(rowbase + r) * 256 + d4 * 4);
    *(float4*)&Xs[r][d4 * 4] = v;
  }
  __syncthreads();

  const int ty = t >> 4;          // 0..15 -> 1 row each
  const int tx = t & 15;          // 0..15 -> 2 h each
  float a0 = 0.f, a1 = 0.f;

#pragma unroll 4
  for (int d4 = 0; d4 < 64; ++d4) {
    int d = d4 * 4;
    float4 x0 = *(const float4*)&Xs[ty][d];
    float2 w0 = *(float2*)&Wt[d + 0][tx * 2];
    float2 w1 = *(float2*)&Wt[d + 1][tx * 2];
    float2 w2 = *(float2*)&Wt[d + 2][tx * 2];
    float2 w3 = *(float2*)&Wt[d + 3][tx * 2];
    a0 = fmaf(x0.x, w0.x, a0); a1 = fmaf(x0.x, w0.y, a1);
    a0 = fmaf(x0.y, w1.x, a0); a1 = fmaf(x0.y, w1.y, a1);
    a0 = fmaf(x0.z, w2.x, a0); a1 = fmaf(x0.z, w2.y, a1);
    a0 = fmaf(x0.w, w3.x, a0); a1 = fmaf(x0.w, w3.y, a1);
  }

  {
    int row = rowbase + ty;
    int h = hh + tx * 2;
    P[row * 64 + h + 0] = a0 * SCALE;
    P[row * 64 + h + 1] = a1 * SCALE;
  }
}

// grid = nsplit*256 WGs of 256 threads (4 waves). wg -> b=wg&7, qg=(wg>>3)&31,
// kh=wg>>8. WG = 8 q-rows (2/wave). FLAT exp-sum softmax (no online max):
// scores bounded |s|<=~24 (W1 + 2*||w||_1) -> e^s <= 2.6e10, l <= 1.3e13,
// all safely f32 -> the per-tile max/alpha/rescale serial chain (10 shuffles +
// exp2 + rescales) is deleted; only l_lane += p per tile, reduced once at end.
// Partials are PLAIN SUMS -> pacc must be f32 (f16 would overflow at p~1e10).
// k+V staged via dbuf global_load_lds, counted vmcnt (R7/R8 proven skeleton).
__global__ __launch_bounds__(256) void attn_kernel(
    const float* __restrict__ qp, const float* __restrict__ kp,
    const uint16_t* __restrict__ vbf, const float* __restrict__ w_v,
    const int* __restrict__ valid_lens, float* __restrict__ out,
    float* __restrict__ pl, float* __restrict__ pacc, int nsplit)
{
  __shared__ float kTs[2][32][64];      // [buf][kj][h], 16B chunks XOR-swizzled by kj&7
  __shared__ uint16_t Vs[2][32][256];   // [buf][kj][d] bf16, linear
  __shared__ float p_s[4][2][32];

  const int t = threadIdx.x;
  const int lane = t & 63;
  const int w = t >> 6;
  const int r2 = lane >> 5;     // score: row-half. PV: kk-half. write: row-half.
  const int kx = lane & 31;     // score: k index.  PV/write: d-chunk c.
  const int wg = blockIdx.x;
  const int b = wg & 7;
  const int qg = (wg >> 3) & 31;
  const int kh = wg >> 8;
  const int row = b * LQ + qg * 8 + w * 2 + r2;

  const int vl = valid_lens[b];
  const int n = (vl > 0) ? vl : LK;   // vl==0 -> uniform softmax over all 512
  const int span = LK / nsplit;
  const int kstart = kh * span;
  int cnt = n - kstart;
  if (cnt > span) cnt = span;
  const int ntiles = (cnt > 0) ? ((cnt + 31) >> 5) : 0;

  if (ntiles == 0) {          // WG-uniform (b,kh only); nsplit>1 guaranteed here
    if (kx == 0) pl[row * nsplit + kh] = 0.f;
    float4 z = {0.f, 0.f, 0.f, 0.f};
    float* pa = pacc + ((size_t)(row * nsplit + kh)) * 256 + kx * 8;
    *(float4*)(pa + 0) = z;
    *(float4*)(pa + 4) = z;
    return;
  }

  // W1*L2E via uniform (scalar) loads
  float W1 = 0.f;
#pragma unroll
  for (int g = 0; g < 16; ++g) {
    float4 wf = *(const float4*)(w_v + g * 4);
    W1 += (wf.x + wf.y) + (wf.z + wf.w);
  }
  const float W1L = W1 * L2E;

  // q-row (pre-scaled) in registers — 64 VGPRs, static indexing only
  float qv[64];
  {
    const float* qrow = qp + (size_t)row * 64;
#pragma unroll
    for (int i = 0; i < 16; ++i) {
      float4 v = *(const float4*)(qrow + i * 4);
      qv[i * 4 + 0] = v.x; qv[i * 4 + 1] = v.y;
      qv[i * 4 + 2] = v.z; qv[i * 4 + 3] = v.w;
    }
  }

  const float* kpb = kp + (size_t)(b * LK) * 64;
  const char* vbc = (const char*)(vbf + (size_t)b * LK * 256);

  // DMA one 32-k tile into buffer BUF: exactly 6 gload16 per wave.
  // k: lane l -> row w*8+(l>>4)(+4), phys chunk l&15, src chunk = phys^(row&7)
  // (XOR involution; LDS dest linear). V: 1KB linear per instr.
#define STAGE(BUF, K0) do { \
    int i0 = w * 2; \
    int kjr0 = i0 * 4 + (lane >> 4); \
    int cph = lane & 15; \
    gload16(kpb + (size_t)((K0) + kjr0) * 64 + (cph ^ (kjr0 & 7)) * 4, \
            &kTs[BUF][i0 * 4][0]); \
    int kjr1 = kjr0 + 4; \
    gload16(kpb + (size_t)((K0) + kjr1) * 64 + (cph ^ (kjr1 & 7)) * 4, \
            &kTs[BUF][i0 * 4 + 4][0]); \
    const char* vsrc = vbc + (size_t)(K0) * 512 + (size_t)w * 4096 + lane * 16; \
    gload16(vsrc + 0 * 1024, &Vs[BUF][w * 8 + 0][0]); \
    gload16(vsrc + 1 * 1024, &Vs[BUF][w * 8 + 2][0]); \
    gload16(vsrc + 2 * 1024, &Vs[BUF][w * 8 + 4][0]); \
    gload16(vsrc + 3 * 1024, &Vs[BUF][w * 8 + 6][0]); \
  } while (0)

  float l = 0.f;                // per-lane partial l (row r2, k-slice kx)
  float acc[16];                // [0..7] row0 partial, [8..15] row1 (this kk-half)
#pragma unroll
  for (int i = 0; i < 16; ++i) acc[i] = 0.f;

  STAGE(0, kstart);

  for (int tt = 0; tt < ntiles; ++tt) {
    const int cur = tt & 1;
    const int k0 = kstart + tt * 32;
    // counted wait: issue next-tile DMA, wait only for THIS tile's 6.
    if (tt + 1 < ntiles) {
      STAGE(cur ^ 1, k0 + 32);
      asm volatile("s_waitcnt vmcnt(6)" ::: "memory");
    } else {
      asm volatile("s_waitcnt vmcnt(0)" ::: "memory");
    }
    __builtin_amdgcn_sched_barrier(0);
    __builtin_amdgcn_s_barrier();        // all waves' tile-tt portions landed
    __builtin_amdgcn_sched_barrier(0);
    __builtin_amdgcn_s_setprio(1);

    // ---- scores: lane = (r2, kx) computes row(r2)'s score at k0+kx ----
    float r0 = 0.f, r1 = 0.f, r2a = 0.f, r3 = 0.f;
#pragma unroll
    for (int g = 0; g < 16; ++g) {
      float4 kf = *(const float4*)&kTs[cur][kx][((g ^ (kx & 7)) << 2)];
      float4 wf = *(const float4*)(w_v + g * 4);        // uniform -> s_load
      r0  = fmaf(wf.x, frcp(1.f + fexp2(qv[g * 4 + 0] + kf.x)), r0);
      r1  = fmaf(wf.y, frcp(1.f + fexp2(qv[g * 4 + 1] + kf.y)), r1);
      r2a = fmaf(wf.z, frcp(1.f + fexp2(qv[g * 4 + 2] + kf.z)), r2a);
      r3  = fmaf(wf.w, frcp(1.f + fexp2(qv[g * 4 + 3] + kf.w)), r3);
    }
    float racc = (r0 + r1) + (r2a + r3);

    // p = e^{score} = exp2(W1L - SCALE*racc); masked -> 0; vl==0 -> 1
    float pe = fexp2(fmaf(-SCALE, racc, W1L));
    int kg = k0 + kx;
    float p;
    if (vl == 0)      p = 1.f;
    else if (kg < n)  p = pe;
    else              p = 0.f;

    l += p;                 // deferred: reduced across lanes once at the end
    p_s[w][r2][kx] = p;     // same-wave handoff (lgkmcnt by compiler)

    // ---- PV: lane = (r2, c): kk in [r2*16,+16), d = c*8..+8, BOTH rows ----
    const int c = kx;
#pragma unroll
    for (int i4 = 0; i4 < 4; ++i4) {
      float4 p0 = *(const float4*)&p_s[w][0][r2 * 16 + i4 * 4];   // row0 p
      float4 p1 = *(const float4*)&p_s[w][1][r2 * 16 + i4 * 4];   // row1 p
#pragma unroll
      for (int jj = 0; jj < 4; ++jj) {
        int kk = r2 * 16 + i4 * 4 + jj;
        uint4 vv = *(const uint4*)&Vs[cur][kk][c * 8];
        float pj0 = (jj == 0) ? p0.x : (jj == 1) ? p0.y : (jj == 2) ? p0.z : p0.w;
        float pj1 = (jj == 0) ? p1.x : (jj == 1) ? p1.y : (jj == 2) ? p1.z : p1.w;
        float f0 = __uint_as_float(vv.x << 16);
        float f1 = __uint_as_float(vv.x & 0xFFFF0000u);
        float f2 = __uint_as_float(vv.y << 16);
        float f3 = __uint_as_float(vv.y & 0xFFFF0000u);
        float f4 = __uint_as_float(vv.z << 16);
        float f5 = __uint_as_float(vv.z & 0xFFFF0000u);
        float f6 = __uint_as_float(vv.w << 16);
        float f7 = __uint_as_float(vv.w & 0xFFFF0000u);
        acc[0] = fmaf(pj0, f0, acc[0]);   acc[8]  = fmaf(pj1, f0, acc[8]);
        acc[1] = fmaf(pj0, f1, acc[1]);   acc[9]  = fmaf(pj1, f1, acc[9]);
        acc[2] = fmaf(pj0, f2, acc[2]);   acc[10] = fmaf(pj1, f2, acc[10]);
        acc[3] = fmaf(pj0, f3, acc[3]);   acc[11] = fmaf(pj1, f3, acc[11]);
        acc[4] = fmaf(pj0, f4, acc[4]);   acc[12] = fmaf(pj1, f4, acc[12]);
        acc[5] = fmaf(pj0, f5, acc[5]);   acc[13] = fmaf(pj1, f5, acc[13]);
        acc[6] = fmaf(pj0, f6, acc[6]);   acc[14] = fmaf(pj1, f6, acc[14]);
        acc[7] = fmaf(pj0, f7, acc[7]);   acc[15] = fmaf(pj1, f7, acc[15]);
      }
    }
    __builtin_amdgcn_s_setprio(0);
    __builtin_amdgcn_sched_barrier(0);
    __builtin_amdgcn_s_barrier();   // readers of buf[cur] done before overwrite
  }
#undef STAGE

  // combine the two kk-half partials (full sums for both rows at own d-chunk)
#pragma unroll
  for (int i = 0; i < 16; ++i) acc[i] += __shfl_xor(acc[i], 32, 64);
  // l: reduce over the 32 kx lanes within the row-half (once, not per tile)
#pragma unroll
  for (int s = 16; s; s >>= 1) l += __shfl_xor(l, s, 64);

  const float* accr = acc + r2 * 8;
  if (nsplit == 1) {
    float inv = 1.f / l;
    float4 o0 = {accr[0] * inv, accr[1] * inv, accr[2] * inv, accr[3] * inv};
    float4 o1 = {accr[4] * inv, accr[5] * inv, accr[6] * inv, accr[7] * inv};
    float* op = out + (size_t)row * 256 + kx * 8;
    *(float4*)(op + 0) = o0;
    *(float4*)(op + 4) = o1;
  } else {
    if (kx == 0) pl[row * nsplit + kh] = l;
    float* pa = pacc + ((size_t)(row * nsplit + kh)) * 256 + kx * 8;
    float4 a0 = {accr[0], accr[1], accr[2], accr[3]};
    float4 a1 = {accr[4], accr[5], accr[6], accr[7]};
    *(float4*)(pa + 0) = a0;
    *(float4*)(pa + 4) = a1;
  }
}

// merge k-split partials: plain sums (no max rescaling needed).
// 256 blocks x 256 thr; 8 rows/block, 32 lanes/row.
__global__ __launch_bounds__(256) void merge_kernel(
    const float* __restrict__ pl, const float* __restrict__ pacc,
    float* __restrict__ out, int nsplit)
{
  const int t = threadIdx.x;
  const int row = blockIdx.x * 8 + (t >> 5);
  const int d8 = t & 31;

  float L = 0.f;
  float o[8];
#pragma unroll
  for (int i = 0; i < 8; ++i) o[i] = 0.f;

  for (int kh = 0; kh < nsplit; ++kh) {
    L += pl[row * nsplit + kh];
    const float* pa = pacc + ((size_t)(row * nsplit + kh)) * 256 + d8 * 8;
    float4 a0 = *(const float4*)(pa + 0);
    float4 a1 = *(const float4*)(pa + 4);
    o[0] += a0.x; o[1] += a0.y; o[2] += a0.z; o[3] += a0.w;
    o[4] += a1.x; o[5] += a1.y; o[6] += a1.z; o[7] += a1.w;
  }
  float inv = 1.f / L;
  float4 o0 = {o[0] * inv, o[1] * inv, o[2] * inv, o[3] * inv};
  float4 o1 = {o[4] * inv, o[5] * inv, o[6] * inv, o[7] * inv};
  float* op = out + (size_t)row * 256 + d8 * 8;
  *(float4*)(op + 0) = o0;
  *(float4*)(op + 4) = o1;
}

extern "C" void kernel_launch(void* const* d_in, const int* in_sizes, int n_in,
                              void* d_out, int out_size, void* d_ws, size_t ws_size,
                              hipStream_t stream) {
  const float* queries    = (const float*)d_in[0];
  const float* keys       = (const float*)d_in[1];
  const float* values     = (const float*)d_in[2];
  const int*   valid_lens = (const int*)d_in[3];
  const float* Wq         = (const float*)d_in[4];
  const float* Wk         = (const float*)d_in[5];
  const float* w_v        = (const float*)d_in[6];
  float* out = (float*)d_out;

  float* ws = (float*)d_ws;
  float* qp  = ws + QP_OFF;
  float* kp  = ws + KP_OFF;
  uint16_t* vbf = (uint16_t*)(ws + VBF_OFF);
  float* pl  = ws + PL_OFF;

  // bytes needed: base 3,670,016 + pl 2048*ns*4 + pacc 2048*ns*1024 (f32)
  int nsplit;
  if      (ws_size >= (size_t)PL_OFF * 4 + 2048u * 4 * 4 + 2048u * 4 * 1024) nsplit = 4;
  else if (ws_size >= (size_t)PL_OFF * 4 + 2048u * 2 * 4 + 2048u * 2 * 1024) nsplit = 2;
  else nsplit = 1;
  float* pacc = pl + (size_t)2048 * nsplit;

  hipLaunchKernelGGL(proj_kernel, dim3(832), dim3(256), 0, stream,
                     queries, keys, values, Wq, Wk, qp, kp, vbf);
  hipLaunchKernelGGL(attn_kernel, dim3(nsplit * 256), dim3(256), 0, stream,
                     qp, kp, vbf, w_v, valid_lens, out, pl, pacc, nsplit);
  if (nsplit > 1) {
    hipLaunchKernelGGL(merge_kernel, dim3(256), dim3(256), 0, stream,
                       pl, pacc, out, nsplit);
  }
}

// Round 12
// 43.381 us; speedup vs baseline: 1.2382x; 1.0434x over previous
//
#include <hip/hip_runtime.h>
#include <hip/hip_bf16.h>
#include <hip/hip_fp16.h>
#include <stdint.h>

#define NB 8
#define LQ 256
#define LK 512
#define NH 64
// 2*log2(e): folded into projections so tanh(x) = 1 - 2/(1+exp2(SCALE*x_sum))
#define SCALE 2.8853900817779268f
#define L2E 1.4426950408889634f

// ws layout (f32 slots)
#define QP_OFF   0            // [2048][64]
#define KP_OFF   131072       // [4096][64] k-proj (plain row-major)
#define VBF_OFF  393216       // [8][512][256] bf16 (524288 f32 slots)
#define PL_OFF   917504       // [2048][ns] l-sums (f32)
// pacc (f32) follows pl; [2048][ns][256]

extern "C" __device__ float __ocml_exp2_f32(float);
static __device__ __forceinline__ float fexp2(float x) {
#if __has_builtin(__builtin_amdgcn_exp2f)
  return __builtin_amdgcn_exp2f(x);
#else
  return __ocml_exp2_f32(x);
#endif
}
static __device__ __forceinline__ float frcp(float x) {
  return __builtin_amdgcn_rcpf(x);
}
static __device__ __forceinline__ uint16_t f2bf(float f) {
  uint32_t u = __float_as_uint(f);
  uint32_t r = (u + 0x7FFFu + ((u >> 16) & 1u)) >> 16;  // RNE
  return (uint16_t)r;
}

// async global->LDS, 16B per lane: dest = wave-uniform LDS base + lane*16,
// src = per-lane global address. Counts against vmcnt.
typedef const __attribute__((address_space(1))) void* gas_ptr;
typedef __attribute__((address_space(3))) void* las_ptr;
static __device__ __forceinline__ void gload16(const void* g, void* l) {
  __builtin_amdgcn_global_load_lds((gas_ptr)g, (las_ptr)l, 16, 0, 0);
}

// blocks 0..63:    q-projection -> qp[row][h] (scaled)   (32 tiles of 64 rows x 2 hh)
// blocks 64..191:  k-projection -> kp[row][h] (scaled)   (64 tiles of 64 rows x 2 hh)
// blocks 192..255: values f32 -> bf16
// R12 redesign: 2 rows x 4 h per thread. Per d4 iter: 4 ds_read_b128 (Wt,
// conflict-free + ty-broadcast) + 2 global b128 (X from L2/L1, 8 lanes share
// each addr) + 32 fma. LDS instr/fma cut 8x vs R11 (proj was LDS-pipe-bound
// ~13us: 320 LDS instr per 512 fma, 3.25 blocks/CU).
__global__ __launch_bounds__(256) void proj_kernel(
    const float* __restrict__ queries, const float* __restrict__ keys,
    const float* __restrict__ values,
    const float* __restrict__ Wq, const float* __restrict__ Wk,
    float* __restrict__ qp, float* __restrict__ kp, uint16_t* __restrict__ vbf)
{
  __shared__ float Wt[256][36];   // [d][h_local 0..31], pad 36 (rows 16B-aligned)
  const int blk = blockIdx.x;
  const int t = threadIdx.x;

  if (blk >= 192) {
    int base = (blk - 192) * 16384 + t * 4;
#pragma unroll
    for (int it = 0; it < 16; ++it) {
      int idx = base + it * 1024;
      float4 v = *(const float4*)(values + idx);
      uint32_t lo = (uint32_t)f2bf(v.x) | ((uint32_t)f2bf(v.y) << 16);
      uint32_t hi = (uint32_t)f2bf(v.z) | ((uint32_t)f2bf(v.w) << 16);
      uint2 pk = {lo, hi};
      *(uint2*)(vbf + idx) = pk;
    }
    return;
  }

  const bool isQ = (blk < 64);
  const int sub = isQ ? blk : (blk - 64);
  const int tile = sub >> 1;
  const int hh = (sub & 1) * 32;
  const int rowbase = tile * 64;
  const float* __restrict__ X = isQ ? queries : keys;
  const float* __restrict__ W = isQ ? Wq : Wk;
  float* __restrict__ P = isQ ? qp : kp;

  // stage W[hh..hh+31][0..255] transposed into Wt[d][hl]
#pragma unroll 4
  for (int it = 0; it < 32; ++it) {
    Wt[t][it] = W[(hh + it) * 256 + t];
  }
  __syncthreads();

  const int ty = t >> 3;          // 0..31 -> 2 rows each
  const int tx = t & 7;           // 0..7  -> 4 h each
  float a0x = 0.f, a0y = 0.f, a0z = 0.f, a0w = 0.f;
  float a1x = 0.f, a1y = 0.f, a1z = 0.f, a1w = 0.f;

  const float* xr0 = X + (size_t)(rowbase + ty * 2) * 256;
  const float* xr1 = xr0 + 256;

#pragma unroll 4
  for (int d4 = 0; d4 < 64; ++d4) {
    int d = d4 * 4;
    float4 x0 = *(const float4*)(xr0 + d);
    float4 x1 = *(const float4*)(xr1 + d);
    float4 w0 = *(const float4*)&Wt[d + 0][tx * 4];
    float4 w1 = *(const float4*)&Wt[d + 1][tx * 4];
    float4 w2 = *(const float4*)&Wt[d + 2][tx * 4];
    float4 w3 = *(const float4*)&Wt[d + 3][tx * 4];
#define STEP(XC, WD) \
    a0x = fmaf(x0.XC, WD.x, a0x); a0y = fmaf(x0.XC, WD.y, a0y); \
    a0z = fmaf(x0.XC, WD.z, a0z); a0w = fmaf(x0.XC, WD.w, a0w); \
    a1x = fmaf(x1.XC, WD.x, a1x); a1y = fmaf(x1.XC, WD.y, a1y); \
    a1z = fmaf(x1.XC, WD.z, a1z); a1w = fmaf(x1.XC, WD.w, a1w);
    STEP(x, w0) STEP(y, w1) STEP(z, w2) STEP(w, w3)
#undef STEP
  }

  {
    int row0 = rowbase + ty * 2;
    int h = hh + tx * 4;
    float4 o0 = {a0x * SCALE, a0y * SCALE, a0z * SCALE, a0w * SCALE};
    float4 o1 = {a1x * SCALE, a1y * SCALE, a1z * SCALE, a1w * SCALE};
    *(float4*)&P[(size_t)row0 * 64 + h] = o0;
    *(float4*)&P[(size_t)(row0 + 1) * 64 + h] = o1;
  }
}

// grid = nsplit*256 WGs of 256 threads (4 waves). wg -> b=wg&7, qg=(wg>>3)&31,
// kh=wg>>8. WG = 8 q-rows (2/wave). FLAT exp-sum softmax (no online max):
// scores bounded |s|<=~24 -> e^s <= 2.6e10, l <= 1.3e13, safely f32.
// Partials are PLAIN SUMS -> pacc f32. k+V staged via dbuf global_load_lds,
// counted vmcnt (R7/R8/R11 proven skeleton — unchanged this round).
__global__ __launch_bounds__(256) void attn_kernel(
    const float* __restrict__ qp, const float* __restrict__ kp,
    const uint16_t* __restrict__ vbf, const float* __restrict__ w_v,
    const int* __restrict__ valid_lens, float* __restrict__ out,
    float* __restrict__ pl, float* __restrict__ pacc, int nsplit)
{
  __shared__ float kTs[2][32][64];      // [buf][kj][h], 16B chunks XOR-swizzled by kj&7
  __shared__ uint16_t Vs[2][32][256];   // [buf][kj][d] bf16, linear
  __shared__ float p_s[4][2][32];

  const int t = threadIdx.x;
  const int lane = t & 63;
  const int w = t >> 6;
  const int r2 = lane >> 5;     // score: row-half. PV: kk-half. write: row-half.
  const int kx = lane & 31;     // score: k index.  PV/write: d-chunk c.
  const int wg = blockIdx.x;
  const int b = wg & 7;
  const int qg = (wg >> 3) & 31;
  const int kh = wg >> 8;
  const int row = b * LQ + qg * 8 + w * 2 + r2;

  const int vl = valid_lens[b];
  const int n = (vl > 0) ? vl : LK;   // vl==0 -> uniform softmax over all 512
  const int span = LK / nsplit;
  const int kstart = kh * span;
  int cnt = n - kstart;
  if (cnt > span) cnt = span;
  const int ntiles = (cnt > 0) ? ((cnt + 31) >> 5) : 0;

  if (ntiles == 0) {          // WG-uniform (b,kh only); nsplit>1 guaranteed here
    if (kx == 0) pl[row * nsplit + kh] = 0.f;
    float4 z = {0.f, 0.f, 0.f, 0.f};
    float* pa = pacc + ((size_t)(row * nsplit + kh)) * 256 + kx * 8;
    *(float4*)(pa + 0) = z;
    *(float4*)(pa + 4) = z;
    return;
  }

  // W1*L2E via uniform (scalar) loads
  float W1 = 0.f;
#pragma unroll
  for (int g = 0; g < 16; ++g) {
    float4 wf = *(const float4*)(w_v + g * 4);
    W1 += (wf.x + wf.y) + (wf.z + wf.w);
  }
  const float W1L = W1 * L2E;

  // q-row (pre-scaled) in registers — 64 VGPRs, static indexing only
  float qv[64];
  {
    const float* qrow = qp + (size_t)row * 64;
#pragma unroll
    for (int i = 0; i < 16; ++i) {
      float4 v = *(const float4*)(qrow + i * 4);
      qv[i * 4 + 0] = v.x; qv[i * 4 + 1] = v.y;
      qv[i * 4 + 2] = v.z; qv[i * 4 + 3] = v.w;
    }
  }

  const float* kpb = kp + (size_t)(b * LK) * 64;
  const char* vbc = (const char*)(vbf + (size_t)b * LK * 256);

  // DMA one 32-k tile into buffer BUF: exactly 6 gload16 per wave.
  // k: lane l -> row w*8+(l>>4)(+4), phys chunk l&15, src chunk = phys^(row&7)
  // (XOR involution; LDS dest linear). V: 1KB linear per instr.
#define STAGE(BUF, K0) do { \
    int i0 = w * 2; \
    int kjr0 = i0 * 4 + (lane >> 4); \
    int cph = lane & 15; \
    gload16(kpb + (size_t)((K0) + kjr0) * 64 + (cph ^ (kjr0 & 7)) * 4, \
            &kTs[BUF][i0 * 4][0]); \
    int kjr1 = kjr0 + 4; \
    gload16(kpb + (size_t)((K0) + kjr1) * 64 + (cph ^ (kjr1 & 7)) * 4, \
            &kTs[BUF][i0 * 4 + 4][0]); \
    const char* vsrc = vbc + (size_t)(K0) * 512 + (size_t)w * 4096 + lane * 16; \
    gload16(vsrc + 0 * 1024, &Vs[BUF][w * 8 + 0][0]); \
    gload16(vsrc + 1 * 1024, &Vs[BUF][w * 8 + 2][0]); \
    gload16(vsrc + 2 * 1024, &Vs[BUF][w * 8 + 4][0]); \
    gload16(vsrc + 3 * 1024, &Vs[BUF][w * 8 + 6][0]); \
  } while (0)

  float l = 0.f;                // per-lane partial l (row r2, k-slice kx)
  float acc[16];                // [0..7] row0 partial, [8..15] row1 (this kk-half)
#pragma unroll
  for (int i = 0; i < 16; ++i) acc[i] = 0.f;

  STAGE(0, kstart);

  for (int tt = 0; tt < ntiles; ++tt) {
    const int cur = tt & 1;
    const int k0 = kstart + tt * 32;
    // counted wait: issue next-tile DMA, wait only for THIS tile's 6.
    if (tt + 1 < ntiles) {
      STAGE(cur ^ 1, k0 + 32);
      asm volatile("s_waitcnt vmcnt(6)" ::: "memory");
    } else {
      asm volatile("s_waitcnt vmcnt(0)" ::: "memory");
    }
    __builtin_amdgcn_sched_barrier(0);
    __builtin_amdgcn_s_barrier();        // all waves' tile-tt portions landed
    __builtin_amdgcn_sched_barrier(0);
    __builtin_amdgcn_s_setprio(1);

    // ---- scores: lane = (r2, kx) computes row(r2)'s score at k0+kx ----
    float r0 = 0.f, r1 = 0.f, r2a = 0.f, r3 = 0.f;
#pragma unroll
    for (int g = 0; g < 16; ++g) {
      float4 kf = *(const float4*)&kTs[cur][kx][((g ^ (kx & 7)) << 2)];
      float4 wf = *(const float4*)(w_v + g * 4);        // uniform -> s_load
      r0  = fmaf(wf.x, frcp(1.f + fexp2(qv[g * 4 + 0] + kf.x)), r0);
      r1  = fmaf(wf.y, frcp(1.f + fexp2(qv[g * 4 + 1] + kf.y)), r1);
      r2a = fmaf(wf.z, frcp(1.f + fexp2(qv[g * 4 + 2] + kf.z)), r2a);
      r3  = fmaf(wf.w, frcp(1.f + fexp2(qv[g * 4 + 3] + kf.w)), r3);
    }
    float racc = (r0 + r1) + (r2a + r3);

    // p = e^{score} = exp2(W1L - SCALE*racc); masked -> 0; vl==0 -> 1
    float pe = fexp2(fmaf(-SCALE, racc, W1L));
    int kg = k0 + kx;
    float p;
    if (vl == 0)      p = 1.f;
    else if (kg < n)  p = pe;
    else              p = 0.f;

    l += p;                 // deferred: reduced across lanes once at the end
    p_s[w][r2][kx] = p;     // same-wave handoff (lgkmcnt by compiler)

    // ---- PV: lane = (r2, c): kk in [r2*16,+16), d = c*8..+8, BOTH rows ----
    const int c = kx;
#pragma unroll
    for (int i4 = 0; i4 < 4; ++i4) {
      float4 p0 = *(const float4*)&p_s[w][0][r2 * 16 + i4 * 4];   // row0 p
      float4 p1 = *(const float4*)&p_s[w][1][r2 * 16 + i4 * 4];   // row1 p
#pragma unroll
      for (int jj = 0; jj < 4; ++jj) {
        int kk = r2 * 16 + i4 * 4 + jj;
        uint4 vv = *(const uint4*)&Vs[cur][kk][c * 8];
        float pj0 = (jj == 0) ? p0.x : (jj == 1) ? p0.y : (jj == 2) ? p0.z : p0.w;
        float pj1 = (jj == 0) ? p1.x : (jj == 1) ? p1.y : (jj == 2) ? p1.z : p1.w;
        float f0 = __uint_as_float(vv.x << 16);
        float f1 = __uint_as_float(vv.x & 0xFFFF0000u);
        float f2 = __uint_as_float(vv.y << 16);
        float f3 = __uint_as_float(vv.y & 0xFFFF0000u);
        float f4 = __uint_as_float(vv.z << 16);
        float f5 = __uint_as_float(vv.z & 0xFFFF0000u);
        float f6 = __uint_as_float(vv.w << 16);
        float f7 = __uint_as_float(vv.w & 0xFFFF0000u);
        acc[0] = fmaf(pj0, f0, acc[0]);   acc[8]  = fmaf(pj1, f0, acc[8]);
        acc[1] = fmaf(pj0, f1, acc[1]);   acc[9]  = fmaf(pj1, f1, acc[9]);
        acc[2] = fmaf(pj0, f2, acc[2]);   acc[10] = fmaf(pj1, f2, acc[10]);
        acc[3] = fmaf(pj0, f3, acc[3]);   acc[11] = fmaf(pj1, f3, acc[11]);
        acc[4] = fmaf(pj0, f4, acc[4]);   acc[12] = fmaf(pj1, f4, acc[12]);
        acc[5] = fmaf(pj0, f5, acc[5]);   acc[13] = fmaf(pj1, f5, acc[13]);
        acc[6] = fmaf(pj0, f6, acc[6]);   acc[14] = fmaf(pj1, f6, acc[14]);
        acc[7] = fmaf(pj0, f7, acc[7]);   acc[15] = fmaf(pj1, f7, acc[15]);
      }
    }
    __builtin_amdgcn_s_setprio(0);
    __builtin_amdgcn_sched_barrier(0);
    __builtin_amdgcn_s_barrier();   // readers of buf[cur] done before overwrite
  }
#undef STAGE

  // combine the two kk-half partials (full sums for both rows at own d-chunk)
#pragma unroll
  for (int i = 0; i < 16; ++i) acc[i] += __shfl_xor(acc[i], 32, 64);
  // l: reduce over the 32 kx lanes within the row-half (once, not per tile)
#pragma unroll
  for (int s = 16; s; s >>= 1) l += __shfl_xor(l, s, 64);

  const float* accr = acc + r2 * 8;
  if (nsplit == 1) {
    float inv = 1.f / l;
    float4 o0 = {accr[0] * inv, accr[1] * inv, accr[2] * inv, accr[3] * inv};
    float4 o1 = {accr[4] * inv, accr[5] * inv, accr[6] * inv, accr[7] * inv};
    float* op = out + (size_t)row * 256 + kx * 8;
    *(float4*)(op + 0) = o0;
    *(float4*)(op + 4) = o1;
  } else {
    if (kx == 0) pl[row * nsplit + kh] = l;
    float* pa = pacc + ((size_t)(row * nsplit + kh)) * 256 + kx * 8;
    float4 a0 = {accr[0], accr[1], accr[2], accr[3]};
    float4 a1 = {accr[4], accr[5], accr[6], accr[7]};
    *(float4*)(pa + 0) = a0;
    *(float4*)(pa + 4) = a1;
  }
}

// merge k-split partials: plain sums (no max rescaling needed).
// 256 blocks x 256 thr; 8 rows/block, 32 lanes/row.
__global__ __launch_bounds__(256) void merge_kernel(
    const float* __restrict__ pl, const float* __restrict__ pacc,
    float* __restrict__ out, int nsplit)
{
  const int t = threadIdx.x;
  const int row = blockIdx.x * 8 + (t >> 5);
  const int d8 = t & 31;

  float L = 0.f;
  float o[8];
#pragma unroll
  for (int i = 0; i < 8; ++i) o[i] = 0.f;

  for (int kh = 0; kh < nsplit; ++kh) {
    L += pl[row * nsplit + kh];
    const float* pa = pacc + ((size_t)(row * nsplit + kh)) * 256 + d8 * 8;
    float4 a0 = *(const float4*)(pa + 0);
    float4 a1 = *(const float4*)(pa + 4);
    o[0] += a0.x; o[1] += a0.y; o[2] += a0.z; o[3] += a0.w;
    o[4] += a1.x; o[5] += a1.y; o[6] += a1.z; o[7] += a1.w;
  }
  float inv = 1.f / L;
  float4 o0 = {o[0] * inv, o[1] * inv, o[2] * inv, o[3] * inv};
  float4 o1 = {o[4] * inv, o[5] * inv, o[6] * inv, o[7] * inv};
  float* op = out + (size_t)row * 256 + d8 * 8;
  *(float4*)(op + 0) = o0;
  *(float4*)(op + 4) = o1;
}

extern "C" void kernel_launch(void* const* d_in, const int* in_sizes, int n_in,
                              void* d_out, int out_size, void* d_ws, size_t ws_size,
                              hipStream_t stream) {
  const float* queries    = (const float*)d_in[0];
  const float* keys       = (const float*)d_in[1];
  const float* values     = (const float*)d_in[2];
  const int*   valid_lens = (const int*)d_in[3];
  const float* Wq         = (const float*)d_in[4];
  const float* Wk         = (const float*)d_in[5];
  const float* w_v        = (const float*)d_in[6];
  float* out = (float*)d_out;

  float* ws = (float*)d_ws;
  float* qp  = ws + QP_OFF;
  float* kp  = ws + KP_OFF;
  uint16_t* vbf = (uint16_t*)(ws + VBF_OFF);
  float* pl  = ws + PL_OFF;

  // bytes needed: base 3,670,016 + pl 2048*ns*4 + pacc 2048*ns*1024 (f32)
  int nsplit;
  if      (ws_size >= (size_t)PL_OFF * 4 + 2048u * 4 * 4 + 2048u * 4 * 1024) nsplit = 4;
  else if (ws_size >= (size_t)PL_OFF * 4 + 2048u * 2 * 4 + 2048u * 2 * 1024) nsplit = 2;
  else nsplit = 1;
  float* pacc = pl + (size_t)2048 * nsplit;

  hipLaunchKernelGGL(proj_kernel, dim3(256), dim3(256), 0, stream,
                     queries, keys, values, Wq, Wk, qp, kp, vbf);
  hipLaunchKernelGGL(attn_kernel, dim3(nsplit * 256), dim3(256), 0, stream,
                     qp, kp, vbf, w_v, valid_lens, out, pl, pacc, nsplit);
  if (nsplit > 1) {
    hipLaunchKernelGGL(merge_kernel, dim3(256), dim3(256), 0, stream,
                       pl, pacc, out, nsplit);
  }
}